// Round 7
// baseline (155.281 us; speedup 1.0000x reference)
//
#include <hip/hip_runtime.h>
#include <hip/hip_fp16.h>
#include <math.h>

#define B_  128
#define E_  128
#define H2_ 512
#define H3_ 1536
#define L_  512
#define V_  50000
#define VL_ 50512   // V + L

typedef short bf16x8 __attribute__((ext_vector_type(8)));
typedef float f32x4 __attribute__((ext_vector_type(4)));
typedef _Float16 half4 __attribute__((ext_vector_type(4)));

__device__ __forceinline__ float fast_tanh(float x) {
    float e = __expf(2.f * x);
    return 1.f - 2.f / (e + 1.f);
}
__device__ __forceinline__ float fast_sigmoid(float x) {
    return 1.f / (1.f + __expf(-x));
}
__device__ __forceinline__ short f2bf(float f) {
    unsigned u = __float_as_uint(f);
    u += 0x7fff + ((u >> 16) & 1);        // RNE
    return (short)(u >> 16);
}

// ---------------- init: bias-broadcast split-K targets, zero pad/rsum8 ----------------
__global__ void k_init(float* __restrict__ gx, float* __restrict__ gh,
                       float* __restrict__ dsl, float* __restrict__ hid,
                       float* __restrict__ out, float* __restrict__ rsum8,
                       const float* __restrict__ b_ih, const float* __restrict__ b_hh,
                       const float* __restrict__ b_ds, const float* __restrict__ b_oh) {
    int i = blockIdx.x * blockDim.x + threadIdx.x;
    if (i < 196608) { gx[i] = b_ih[i % 1536]; return; }
    i -= 196608;
    if (i < 196608) { gh[i] = b_hh[i % 1536]; return; }
    i -= 196608;
    if (i < 65536)  { dsl[i] = b_ds[i & 511]; return; }
    i -= 65536;
    if (i < 16384)  { hid[i] = b_oh[i & 127]; return; }
    i -= 16384;
    if (i < 65536)  { out[(size_t)(i >> 9) * VL_ + V_ + (i & 511)] = 0.f; return; }
    i -= 65536;
    if (i < 1024)   rsum8[i] = 0.f;
}

// ---------------- gx & gh GEMMs, split-K, one kernel (z: 0-1 gx, 2-5 gh) -------------
__global__ void k_gates(const int* __restrict__ ids, const float* __restrict__ tab,
                        const float* __restrict__ hidden,
                        const float* __restrict__ W_ih, const float* __restrict__ W_hh,
                        float* __restrict__ gx, float* __restrict__ gh) {
    __shared__ float As[32][36];
    __shared__ float Ws[32][36];
    int z = blockIdx.z;
    int which = (z < 2) ? 0 : 1;
    int kbeg  = which ? (z - 2) * 128 : z * 64;
    int kiter = which ? 4 : 2;
    const float* W = which ? W_hh : W_ih;
    int ldw = which ? H2_ : E_;
    float* C = which ? gh : gx;
    int bm = blockIdx.x * 32, bn = blockIdx.y * 32;
    int tid = threadIdx.x;
    int tm0 = (tid / 16) * 2, tn0 = (tid % 16) * 2;
    float acc[2][2] = {};
    for (int it = 0; it < kiter; ++it) {
        int k0 = kbeg + it * 32;
        for (int v = tid; v < 256; v += 256) {
            int m = v >> 3, q = (v & 7) << 2;
            int gm = bm + m;
            const float* arow = which ? (hidden + (size_t)gm * H2_)
                                      : (tab + (size_t)ids[gm] * E_);
            float4 x = *(const float4*)(arow + k0 + q);
            As[q+0][m] = x.x; As[q+1][m] = x.y; As[q+2][m] = x.z; As[q+3][m] = x.w;
        }
        for (int v = tid; v < 256; v += 256) {
            int n = v >> 3, q = (v & 7) << 2;
            float4 x = *(const float4*)(W + (size_t)(bn + n) * ldw + k0 + q);
            Ws[q+0][n] = x.x; Ws[q+1][n] = x.y; Ws[q+2][n] = x.z; Ws[q+3][n] = x.w;
        }
        __syncthreads();
        #pragma unroll
        for (int kk = 0; kk < 32; ++kk) {
            float a0 = As[kk][tm0], a1 = As[kk][tm0+1];
            float w0 = Ws[kk][tn0], w1 = Ws[kk][tn0+1];
            acc[0][0] += a0*w0; acc[0][1] += a0*w1;
            acc[1][0] += a1*w0; acc[1][1] += a1*w1;
        }
        __syncthreads();
    }
    #pragma unroll
    for (int i = 0; i < 2; ++i)
        #pragma unroll
        for (int j = 0; j < 2; ++j)
            atomicAdd(&C[(size_t)(bm+tm0+i) * H3_ + bn+tn0+j], acc[i][j]);
}

// ---------------- generic tiled GEMM (dsl/hid), split-K atomic ----------------
template<int BM, int BN, int BK, int TM, int TN, int SPLITK>
__global__ void gemm_t(const float* __restrict__ A, int lda,
                       const float* __restrict__ W, int ldw,
                       float* __restrict__ C, int ldc,
                       int N, int K) {
    __shared__ float As[BK][BM + 4];
    __shared__ float Ws[BK][BN + 4];
    int bm = blockIdx.x * BM, bn = blockIdx.y * BN;
    int tid = threadIdx.x;
    constexpr int NT = BN / TN;
    int tm0 = (tid / NT) * TM;
    int tn0 = (tid % NT) * TN;
    int kchunk = K / SPLITK;
    int kbeg = blockIdx.z * kchunk;
    float acc[TM][TN] = {};
    for (int k0 = kbeg; k0 < kbeg + kchunk; k0 += BK) {
        #pragma unroll
        for (int v = tid; v < BM * BK / 4; v += 256) {
            int m = v / (BK / 4), q = (v % (BK / 4)) * 4;
            float4 x = *(const float4*)(A + (size_t)(bm + m) * lda + k0 + q);
            As[q+0][m] = x.x; As[q+1][m] = x.y; As[q+2][m] = x.z; As[q+3][m] = x.w;
        }
        #pragma unroll
        for (int v = tid; v < BN * BK / 4; v += 256) {
            int n = v / (BK / 4), q = (v % (BK / 4)) * 4;
            float4 x = *(const float4*)(W + (size_t)(bn + n) * ldw + k0 + q);
            Ws[q+0][n] = x.x; Ws[q+1][n] = x.y; Ws[q+2][n] = x.z; Ws[q+3][n] = x.w;
        }
        __syncthreads();
        #pragma unroll
        for (int kk = 0; kk < BK; ++kk) {
            float a[TM], w[TN];
            #pragma unroll
            for (int i = 0; i < TM; ++i) a[i] = As[kk][tm0 + i];
            #pragma unroll
            for (int j = 0; j < TN; ++j) w[j] = Ws[kk][tn0 + j];
            #pragma unroll
            for (int i = 0; i < TM; ++i)
                #pragma unroll
                for (int j = 0; j < TN; ++j) acc[i][j] += a[i] * w[j];
        }
        __syncthreads();
    }
    #pragma unroll
    for (int i = 0; i < TM; ++i)
        #pragma unroll
        for (int j = 0; j < TN; ++j)
            atomicAdd(&C[(size_t)(bm+tm0+i) * ldc + bn+tn0+j], acc[i][j]);
}

// ---------------- GRU gates (+ zero ctx region) ----------------
__global__ void k_gru(const float* __restrict__ gx, const float* __restrict__ gh,
                      const float* __restrict__ h0,
                      float* __restrict__ comb, float* __restrict__ hout) {
    int idx = blockIdx.x * blockDim.x + threadIdx.x;  // B*H2 = 65536
    int b = idx >> 9, h = idx & 511;
    const float* gxb = gx + b * H3_;
    const float* ghb = gh + b * H3_;
    float xr = gxb[h], xz = gxb[H2_ + h], xn = gxb[2 * H2_ + h];
    float hr = ghb[h], hz = ghb[H2_ + h], hn = ghb[2 * H2_ + h];
    float r = fast_sigmoid(xr + hr);
    float z = fast_sigmoid(xz + hz);
    float n = fast_tanh(xn + r * hn);
    float hv = (1.f - z) * n + z * h0[idx];
    comb[b * (2 * H2_) + h] = hv;
    comb[b * (2 * H2_) + H2_ + h] = 0.f;
    hout[idx] = hv;
}

// ---------------- attention scores: one wave = 8 l's x same b (deep in-flight) -------
__global__ void k_scores(const float* __restrict__ enc, const float* __restrict__ dsl,
                         const float* __restrict__ w_h, const float* __restrict__ att_v,
                         float* __restrict__ scores) {
    int wid = (blockIdx.x << 2) + (threadIdx.x >> 6);  // 8192 waves
    int lane = threadIdx.x & 63;
    int b = wid & 127, lg = wid >> 7;                  // 64 l-groups of 8
    int l0 = lg << 3;
    const float4* d4 = (const float4*)(dsl + b * H2_);
    const float4* w4 = (const float4*)w_h;
    const float4* v4 = (const float4*)att_v;
    float4 d0 = d4[lane], d1 = d4[lane + 64];
    float4 w0 = w4[lane], w1 = w4[lane + 64];
    float4 v0 = v4[lane], v1 = v4[lane + 64];
    float4 e0[8], e1[8];
    #pragma unroll
    for (int q = 0; q < 8; ++q) {
        const float4* e4 = (const float4*)(enc + ((size_t)((l0 + q) * B_ + b)) * H2_);
        e0[q] = e4[lane];
        e1[q] = e4[lane + 64];
    }
    float s[8];
    #pragma unroll
    for (int q = 0; q < 8; ++q) {
        float t;
        t  = v0.x * fast_tanh(w0.x * e0[q].x + d0.x);
        t += v0.y * fast_tanh(w0.y * e0[q].y + d0.y);
        t += v0.z * fast_tanh(w0.z * e0[q].z + d0.z);
        t += v0.w * fast_tanh(w0.w * e0[q].w + d0.w);
        t += v1.x * fast_tanh(w1.x * e1[q].x + d1.x);
        t += v1.y * fast_tanh(w1.y * e1[q].y + d1.y);
        t += v1.z * fast_tanh(w1.z * e1[q].z + d1.z);
        t += v1.w * fast_tanh(w1.w * e1[q].w + d1.w);
        s[q] = t;
    }
    #pragma unroll
    for (int q = 0; q < 8; ++q) {
        float t = s[q];
        #pragma unroll
        for (int o = 32; o; o >>= 1) t += __shfl_xor(t, o);
        if (lane == 0) scores[(l0 + q) * B_ + b] = t;
    }
}

// ---------------- softmax over batch axis (per l) ----------------
__global__ void k_softmax(const float* __restrict__ scores, float* __restrict__ attn) {
    int l = blockIdx.x, lane = threadIdx.x;   // 64 threads
    float s0 = scores[l * B_ + lane], s1 = scores[l * B_ + lane + 64];
    float m = fmaxf(s0, s1);
    #pragma unroll
    for (int o = 32; o; o >>= 1) m = fmaxf(m, __shfl_xor(m, o));
    float e0 = __expf(s0 - m), e1 = __expf(s1 - m);
    float t = e0 + e1;
    #pragma unroll
    for (int o = 32; o; o >>= 1) t += __shfl_xor(t, o);
    float inv = 1.f / t;
    attn[l * B_ + lane] = e0 * inv;
    attn[l * B_ + lane + 64] = e1 * inv;
}

// ---------------- context: block (b, l-chunk of 16), 128 thr, 16 loads in flight -----
__global__ void k_context(const float* __restrict__ enc, const float* __restrict__ attn,
                          float* __restrict__ comb) {
    int b = blockIdx.x;
    int l0 = blockIdx.y << 4;            // 32 chunks of 16
    int tid = threadIdx.x;               // 128 threads, float4 over h
    __shared__ float a_s[16];
    if (tid < 16) a_s[tid] = attn[(l0 + tid) * B_ + b];
    __syncthreads();
    const float4* e = (const float4*)(enc + ((size_t)l0 * B_ + b) * H2_) + tid;
    float4 c = make_float4(0.f, 0.f, 0.f, 0.f);
    #pragma unroll
    for (int i = 0; i < 16; ++i) {
        float4 x = e[(size_t)i * (B_ * H2_ / 4)];
        float a = a_s[i];
        c.x += a * x.x; c.y += a * x.y; c.z += a * x.z; c.w += a * x.w;
    }
    float* dst = comb + b * (2 * H2_) + H2_ + tid * 4;
    atomicAdd(dst + 0, c.x); atomicAdd(dst + 1, c.y);
    atomicAdd(dst + 2, c.z); atomicAdd(dst + 3, c.w);
}

// ---------------- p_gen: one wave per b ----------------
__global__ void k_pgen(const float* __restrict__ comb,
                       const int* __restrict__ ids, const float* __restrict__ tab,
                       const float* __restrict__ W_ptr, const float* __restrict__ b_ptr,
                       float* __restrict__ pgen) {
    int b = blockIdx.x, lane = threadIdx.x;  // 64 threads
    float s = 0.f;
    for (int j = lane; j < 2 * H2_; j += 64) s += W_ptr[j] * comb[b * (2 * H2_) + j];
    const float* erow = tab + (size_t)ids[b] * E_;
    for (int j = lane; j < E_; j += 64) s += W_ptr[2 * H2_ + j] * erow[j];
    #pragma unroll
    for (int o = 32; o; o >>= 1) s += __shfl_xor(s, o);
    if (lane == 0) pgen[b] = fast_sigmoid(s + b_ptr[0]);
}

// ---------------- vocab MFMA GEMM: eout = exp(hid@Wov^T + bov) as half, rsum8 --------
__global__ void k_vocab(const float* __restrict__ hid, const float* __restrict__ Wov,
                        const float* __restrict__ bov, _Float16* __restrict__ eout,
                        float* __restrict__ rsum8) {
    __shared__ float sm[4][128];
    int L = threadIdx.x & 63, w = threadIdx.x >> 6;
    int lrow = L & 15, lk = L >> 4;
    int n0 = blockIdx.x * 128 + w * 32;

    bf16x8 bfr[2][4];
    #pragma unroll
    for (int nt = 0; nt < 2; ++nt) {
        int n = n0 + nt * 16 + lrow;
        #pragma unroll
        for (int kk = 0; kk < 4; ++kk) {
            bf16x8 f;
            if (n < V_) {
                const float* p = Wov + (size_t)n * 128 + kk * 32 + lk * 8;
                float4 x = *(const float4*)p, y = *(const float4*)(p + 4);
                f[0]=f2bf(x.x); f[1]=f2bf(x.y); f[2]=f2bf(x.z); f[3]=f2bf(x.w);
                f[4]=f2bf(y.x); f[5]=f2bf(y.y); f[6]=f2bf(y.z); f[7]=f2bf(y.w);
            } else {
                #pragma unroll
                for (int j = 0; j < 8; ++j) f[j] = 0;
            }
            bfr[nt][kk] = f;
        }
    }
    f32x4 acc[8][2] = {};
    #pragma unroll
    for (int mt = 0; mt < 8; ++mt) {
        bf16x8 afr[4];
        #pragma unroll
        for (int kk = 0; kk < 4; ++kk) {
            const float* p = hid + (size_t)(mt * 16 + lrow) * 128 + kk * 32 + lk * 8;
            float4 x = *(const float4*)p, y = *(const float4*)(p + 4);
            bf16x8 f;
            f[0]=f2bf(x.x); f[1]=f2bf(x.y); f[2]=f2bf(x.z); f[3]=f2bf(x.w);
            f[4]=f2bf(y.x); f[5]=f2bf(y.y); f[6]=f2bf(y.z); f[7]=f2bf(y.w);
            afr[kk] = f;
        }
        #pragma unroll
        for (int nt = 0; nt < 2; ++nt)
            #pragma unroll
            for (int kk = 0; kk < 4; ++kk)
                acc[mt][nt] = __builtin_amdgcn_mfma_f32_16x16x32_bf16(
                    afr[kk], bfr[nt][kk], acc[mt][nt], 0, 0, 0);
    }
    float bv[2];
    #pragma unroll
    for (int nt = 0; nt < 2; ++nt) {
        int n = n0 + nt * 16 + lrow;
        bv[nt] = (n < V_) ? bov[n] : 0.f;
    }
    float rs[8][4];
    #pragma unroll
    for (int mt = 0; mt < 8; ++mt) {
        #pragma unroll
        for (int r = 0; r < 4; ++r) rs[mt][r] = 0.f;
        #pragma unroll
        for (int nt = 0; nt < 2; ++nt) {
            int n = n0 + nt * 16 + lrow;
            if (n < V_) {
                #pragma unroll
                for (int r = 0; r < 4; ++r) {
                    int row = mt * 16 + lk * 4 + r;
                    float e = __expf(acc[mt][nt][r] + bv[nt]);
                    eout[(size_t)row * V_ + n] = (_Float16)e;
                    rs[mt][r] += e;
                }
            }
        }
    }
    #pragma unroll
    for (int o = 1; o < 16; o <<= 1)
        #pragma unroll
        for (int mt = 0; mt < 8; ++mt)
            #pragma unroll
            for (int r = 0; r < 4; ++r) rs[mt][r] += __shfl_xor(rs[mt][r], o);
    if (lrow == 0) {
        #pragma unroll
        for (int mt = 0; mt < 8; ++mt)
            #pragma unroll
            for (int r = 0; r < 4; ++r)
                sm[w][mt * 16 + lk * 4 + r] = rs[mt][r];
    }
    __syncthreads();
    if (threadIdx.x < 128) {
        float p = sm[0][threadIdx.x] + sm[1][threadIdx.x]
                + sm[2][threadIdx.x] + sm[3][threadIdx.x];
        atomicAdd(&rsum8[(blockIdx.x & 7) * 128 + threadIdx.x], p);
    }
}

// ---------------- finalize: read half exp, scale by pgen/rsum, write f32 -------------
__global__ void k_final(const _Float16* __restrict__ eout, float* __restrict__ out,
                        const float* __restrict__ pgen, const float* __restrict__ rsum8) {
    int b = blockIdx.y, chunk = blockIdx.x, tid = threadIdx.x;
    __shared__ float sc;
    if (tid == 0) {
        float s = 0.f;
        #pragma unroll
        for (int j = 0; j < 8; ++j) s += rsum8[j * 128 + b];
        sc = pgen[b] / s;
    }
    __syncthreads();
    int j = chunk * 256 + tid;
    if (j < V_ / 4) {
        half4 h = ((const half4*)(eout + (size_t)b * V_))[j];
        float4 x;
        x.x = (float)h[0] * sc; x.y = (float)h[1] * sc;
        x.z = (float)h[2] * sc; x.w = (float)h[3] * sc;
        ((float4*)(out + (size_t)b * VL_))[j] = x;
    }
}

// ---------------- scatter copy distribution ----------------
__global__ void k_scatter(float* __restrict__ out, const int* __restrict__ full_input,
                          const float* __restrict__ attn, const float* __restrict__ pgen) {
    int idx = blockIdx.x * blockDim.x + threadIdx.x;  // L*B = 65536
    int b = idx & 127;
    int tok = full_input[idx];
    atomicAdd(&out[(size_t)b * VL_ + tok], (1.f - pgen[b]) * attn[idx]);
}

extern "C" void kernel_launch(void* const* d_in, const int* in_sizes, int n_in,
                              void* d_out, int out_size, void* d_ws, size_t ws_size,
                              hipStream_t stream) {
    const int*   input_ids = (const int*)d_in[0];
    const float* hidden    = (const float*)d_in[1];
    const float* enc       = (const float*)d_in[2];
    const int*   full_in   = (const int*)d_in[3];
    const float* emb_tab   = (const float*)d_in[4];
    const float* W_ih      = (const float*)d_in[5];
    const float* W_hh      = (const float*)d_in[6];
    const float* b_ih      = (const float*)d_in[7];
    const float* b_hh      = (const float*)d_in[8];
    const float* W_ds      = (const float*)d_in[9];
    const float* b_ds      = (const float*)d_in[10];
    const float* w_h       = (const float*)d_in[11];
    const float* att_v     = (const float*)d_in[12];
    const float* W_oh      = (const float*)d_in[13];
    const float* b_oh      = (const float*)d_in[14];
    const float* W_ov      = (const float*)d_in[15];
    const float* b_ov      = (const float*)d_in[16];
    const float* W_ptr     = (const float*)d_in[17];
    const float* b_ptr     = (const float*)d_in[18];

    float* out = (float*)d_out;
    float* p_final = out;                                  // [B, VL]
    float* h_out   = out + (size_t)B_ * VL_;               // [B, H2]
    float* attn    = out + (size_t)B_ * VL_ + B_ * H2_;    // [L, B]

    float* ws = (float*)d_ws;
    float* gx     = ws;            // 196608
    float* gh     = gx + 196608;   // 196608
    float* comb   = gh + 196608;   // 131072  [B, 2*H2]: h_new | context
    float* dsl    = comb + 131072; // 65536
    float* scores = dsl + 65536;   // 65536
    float* hid    = scores + 65536;// 16384
    float* pgen   = hid + 16384;   // 128
    float* rsum8  = pgen + 128;    // 1024
    _Float16* eout = (_Float16*)(rsum8 + 1024);  // 128*50000 halves = 12.8 MB

    // 0. init bias targets / zero pad & rsum8
    k_init<<<dim3(2116), dim3(256), 0, stream>>>(gx, gh, dsl, hid, out, rsum8,
                                                 b_ih, b_hh, b_ds, b_oh);
    // 1. gx & gh GEMMs (split-K, atomic)
    k_gates<<<dim3(4,48,6), dim3(256), 0, stream>>>(input_ids, emb_tab, hidden,
                                                    W_ih, W_hh, gx, gh);
    // 2. GRU -> h_new (+ zero ctx region)
    k_gru<<<dim3(256), dim3(256), 0, stream>>>(gx, gh, hidden, comb, h_out);
    // 3. dsl = h_new @ W_ds^T + b_ds (split-K 4)
    gemm_t<32,32,32,2,2,4><<<dim3(4,16,4), dim3(256), 0, stream>>>(
        comb, 2*H2_, W_ds, H2_, dsl, H2_, H2_, H2_);
    // 4. attention scores (8 l's per wave)
    k_scores<<<dim3(2048), dim3(256), 0, stream>>>(enc, dsl, w_h, att_v, scores);
    // 5. softmax over batch axis
    k_softmax<<<dim3(L_), dim3(64), 0, stream>>>(scores, attn);
    // 6. context (16-l chunks, deep in-flight)
    k_context<<<dim3(B_, 32), dim3(128), 0, stream>>>(enc, attn, comb);
    // 7. p_gen
    k_pgen<<<dim3(B_), dim3(64), 0, stream>>>(comb, input_ids, emb_tab, W_ptr, b_ptr, pgen);
    // 8. hid = comb @ W_oh^T + b_oh (split-K 8)
    gemm_t<32,32,32,2,2,8><<<dim3(4,4,8), dim3(256), 0, stream>>>(
        comb, 2*H2_, W_oh, 2*H2_, hid, E_, E_, 2*H2_);
    // 9. vocab MFMA: eout = exp(logits) (half), rsum8 partials
    k_vocab<<<dim3(391), dim3(256), 0, stream>>>(hid, W_ov, b_ov, eout, rsum8);
    // 10. scale by pgen/rsum: half -> f32
    k_final<<<dim3(49, 128), dim3(256), 0, stream>>>(eout, p_final, pgen, rsum8);
    // 11. scatter
    k_scatter<<<dim3(L_*B_/256), dim3(256), 0, stream>>>(p_final, full_in, attn, pgen);
}

// Round 8
// 146.288 us; speedup vs baseline: 1.0615x; 1.0615x over previous
//
#include <hip/hip_runtime.h>
#include <math.h>

#define B_  128
#define E_  128
#define H2_ 512
#define H3_ 1536
#define L_  512
#define V_  50000
#define VL_ 50512   // V + L

typedef short bf16x8 __attribute__((ext_vector_type(8)));
typedef float f32x4 __attribute__((ext_vector_type(4)));

__device__ __forceinline__ float fast_tanh(float x) {
    float e = __expf(2.f * x);
    return 1.f - 2.f / (e + 1.f);
}
__device__ __forceinline__ float fast_sigmoid(float x) {
    return 1.f / (1.f + __expf(-x));
}
__device__ __forceinline__ short f2bf(float f) {
    unsigned u = __float_as_uint(f);
    u += 0x7fff + ((u >> 16) & 1);        // RNE
    return (short)(u >> 16);
}

// ---------------- init: bias-broadcast split-K targets, zero pad/rsum8 ----------------
__global__ void k_init(float* __restrict__ gx, float* __restrict__ gh,
                       float* __restrict__ dsl, float* __restrict__ hid,
                       float* __restrict__ out, float* __restrict__ rsum8,
                       const float* __restrict__ b_ih, const float* __restrict__ b_hh,
                       const float* __restrict__ b_ds, const float* __restrict__ b_oh) {
    int i = blockIdx.x * blockDim.x + threadIdx.x;
    if (i < 196608) { gx[i] = b_ih[i % 1536]; return; }
    i -= 196608;
    if (i < 196608) { gh[i] = b_hh[i % 1536]; return; }
    i -= 196608;
    if (i < 65536)  { dsl[i] = b_ds[i & 511]; return; }
    i -= 65536;
    if (i < 16384)  { hid[i] = b_oh[i & 127]; return; }
    i -= 16384;
    if (i < 65536)  { out[(size_t)(i >> 9) * VL_ + V_ + (i & 511)] = 0.f; return; }
    i -= 65536;
    if (i < 1024)   rsum8[i] = 0.f;
}

// ---------------- gx & gh GEMMs, split-K, one kernel (z: 0-1 gx, 2-5 gh) -------------
__global__ void k_gates(const int* __restrict__ ids, const float* __restrict__ tab,
                        const float* __restrict__ hidden,
                        const float* __restrict__ W_ih, const float* __restrict__ W_hh,
                        float* __restrict__ gx, float* __restrict__ gh) {
    __shared__ float As[32][36];
    __shared__ float Ws[32][36];
    int z = blockIdx.z;
    int which = (z < 2) ? 0 : 1;
    int kbeg  = which ? (z - 2) * 128 : z * 64;
    int kiter = which ? 4 : 2;
    const float* W = which ? W_hh : W_ih;
    int ldw = which ? H2_ : E_;
    float* C = which ? gh : gx;
    int bm = blockIdx.x * 32, bn = blockIdx.y * 32;
    int tid = threadIdx.x;
    int tm0 = (tid / 16) * 2, tn0 = (tid % 16) * 2;
    float acc[2][2] = {};
    for (int it = 0; it < kiter; ++it) {
        int k0 = kbeg + it * 32;
        for (int v = tid; v < 256; v += 256) {
            int m = v >> 3, q = (v & 7) << 2;
            int gm = bm + m;
            const float* arow = which ? (hidden + (size_t)gm * H2_)
                                      : (tab + (size_t)ids[gm] * E_);
            float4 x = *(const float4*)(arow + k0 + q);
            As[q+0][m] = x.x; As[q+1][m] = x.y; As[q+2][m] = x.z; As[q+3][m] = x.w;
        }
        for (int v = tid; v < 256; v += 256) {
            int n = v >> 3, q = (v & 7) << 2;
            float4 x = *(const float4*)(W + (size_t)(bn + n) * ldw + k0 + q);
            Ws[q+0][n] = x.x; Ws[q+1][n] = x.y; Ws[q+2][n] = x.z; Ws[q+3][n] = x.w;
        }
        __syncthreads();
        #pragma unroll
        for (int kk = 0; kk < 32; ++kk) {
            float a0 = As[kk][tm0], a1 = As[kk][tm0+1];
            float w0 = Ws[kk][tn0], w1 = Ws[kk][tn0+1];
            acc[0][0] += a0*w0; acc[0][1] += a0*w1;
            acc[1][0] += a1*w0; acc[1][1] += a1*w1;
        }
        __syncthreads();
    }
    #pragma unroll
    for (int i = 0; i < 2; ++i)
        #pragma unroll
        for (int j = 0; j < 2; ++j)
            atomicAdd(&C[(size_t)(bm+tm0+i) * H3_ + bn+tn0+j], acc[i][j]);
}

// ---------------- generic tiled GEMM (dsl/hid), split-K atomic ----------------
template<int BM, int BN, int BK, int TM, int TN, int SPLITK>
__global__ void gemm_t(const float* __restrict__ A, int lda,
                       const float* __restrict__ W, int ldw,
                       float* __restrict__ C, int ldc,
                       int N, int K) {
    __shared__ float As[BK][BM + 4];
    __shared__ float Ws[BK][BN + 4];
    int bm = blockIdx.x * BM, bn = blockIdx.y * BN;
    int tid = threadIdx.x;
    constexpr int NT = BN / TN;
    int tm0 = (tid / NT) * TM;
    int tn0 = (tid % NT) * TN;
    int kchunk = K / SPLITK;
    int kbeg = blockIdx.z * kchunk;
    float acc[TM][TN] = {};
    for (int k0 = kbeg; k0 < kbeg + kchunk; k0 += BK) {
        #pragma unroll
        for (int v = tid; v < BM * BK / 4; v += 256) {
            int m = v / (BK / 4), q = (v % (BK / 4)) * 4;
            float4 x = *(const float4*)(A + (size_t)(bm + m) * lda + k0 + q);
            As[q+0][m] = x.x; As[q+1][m] = x.y; As[q+2][m] = x.z; As[q+3][m] = x.w;
        }
        #pragma unroll
        for (int v = tid; v < BN * BK / 4; v += 256) {
            int n = v / (BK / 4), q = (v % (BK / 4)) * 4;
            float4 x = *(const float4*)(W + (size_t)(bn + n) * ldw + k0 + q);
            Ws[q+0][n] = x.x; Ws[q+1][n] = x.y; Ws[q+2][n] = x.z; Ws[q+3][n] = x.w;
        }
        __syncthreads();
        #pragma unroll
        for (int kk = 0; kk < BK; ++kk) {
            float a[TM], w[TN];
            #pragma unroll
            for (int i = 0; i < TM; ++i) a[i] = As[kk][tm0 + i];
            #pragma unroll
            for (int j = 0; j < TN; ++j) w[j] = Ws[kk][tn0 + j];
            #pragma unroll
            for (int i = 0; i < TM; ++i)
                #pragma unroll
                for (int j = 0; j < TN; ++j) acc[i][j] += a[i] * w[j];
        }
        __syncthreads();
    }
    #pragma unroll
    for (int i = 0; i < TM; ++i)
        #pragma unroll
        for (int j = 0; j < TN; ++j)
            atomicAdd(&C[(size_t)(bm+tm0+i) * ldc + bn+tn0+j], acc[i][j]);
}

// ---------------- GRU gates (+ zero ctx region) ----------------
__global__ void k_gru(const float* __restrict__ gx, const float* __restrict__ gh,
                      const float* __restrict__ h0,
                      float* __restrict__ comb, float* __restrict__ hout) {
    int idx = blockIdx.x * blockDim.x + threadIdx.x;  // B*H2 = 65536
    int b = idx >> 9, h = idx & 511;
    const float* gxb = gx + b * H3_;
    const float* ghb = gh + b * H3_;
    float xr = gxb[h], xz = gxb[H2_ + h], xn = gxb[2 * H2_ + h];
    float hr = ghb[h], hz = ghb[H2_ + h], hn = ghb[2 * H2_ + h];
    float r = fast_sigmoid(xr + hr);
    float z = fast_sigmoid(xz + hz);
    float n = fast_tanh(xn + r * hn);
    float hv = (1.f - z) * n + z * h0[idx];
    comb[b * (2 * H2_) + h] = hv;
    comb[b * (2 * H2_) + H2_ + h] = 0.f;
    hout[idx] = hv;
}

// ---------------- attention scores: one wave = 8 l's x same b (deep in-flight) -------
__global__ void k_scores(const float* __restrict__ enc, const float* __restrict__ dsl,
                         const float* __restrict__ w_h, const float* __restrict__ att_v,
                         float* __restrict__ scores) {
    int wid = (blockIdx.x << 2) + (threadIdx.x >> 6);  // 8192 waves
    int lane = threadIdx.x & 63;
    int b = wid & 127, lg = wid >> 7;                  // 64 l-groups of 8
    int l0 = lg << 3;
    const float4* d4 = (const float4*)(dsl + b * H2_);
    const float4* w4 = (const float4*)w_h;
    const float4* v4 = (const float4*)att_v;
    float4 d0 = d4[lane], d1 = d4[lane + 64];
    float4 w0 = w4[lane], w1 = w4[lane + 64];
    float4 v0 = v4[lane], v1 = v4[lane + 64];
    float4 e0[8], e1[8];
    #pragma unroll
    for (int q = 0; q < 8; ++q) {
        const float4* e4 = (const float4*)(enc + ((size_t)((l0 + q) * B_ + b)) * H2_);
        e0[q] = e4[lane];
        e1[q] = e4[lane + 64];
    }
    float s[8];
    #pragma unroll
    for (int q = 0; q < 8; ++q) {
        float t;
        t  = v0.x * fast_tanh(w0.x * e0[q].x + d0.x);
        t += v0.y * fast_tanh(w0.y * e0[q].y + d0.y);
        t += v0.z * fast_tanh(w0.z * e0[q].z + d0.z);
        t += v0.w * fast_tanh(w0.w * e0[q].w + d0.w);
        t += v1.x * fast_tanh(w1.x * e1[q].x + d1.x);
        t += v1.y * fast_tanh(w1.y * e1[q].y + d1.y);
        t += v1.z * fast_tanh(w1.z * e1[q].z + d1.z);
        t += v1.w * fast_tanh(w1.w * e1[q].w + d1.w);
        s[q] = t;
    }
    #pragma unroll
    for (int q = 0; q < 8; ++q) {
        float t = s[q];
        #pragma unroll
        for (int o = 32; o; o >>= 1) t += __shfl_xor(t, o);
        if (lane == 0) scores[(l0 + q) * B_ + b] = t;
    }
}

// ---------------- softmax over batch axis (per l) ----------------
__global__ void k_softmax(const float* __restrict__ scores, float* __restrict__ attn) {
    int l = blockIdx.x, lane = threadIdx.x;   // 64 threads
    float s0 = scores[l * B_ + lane], s1 = scores[l * B_ + lane + 64];
    float m = fmaxf(s0, s1);
    #pragma unroll
    for (int o = 32; o; o >>= 1) m = fmaxf(m, __shfl_xor(m, o));
    float e0 = __expf(s0 - m), e1 = __expf(s1 - m);
    float t = e0 + e1;
    #pragma unroll
    for (int o = 32; o; o >>= 1) t += __shfl_xor(t, o);
    float inv = 1.f / t;
    attn[l * B_ + lane] = e0 * inv;
    attn[l * B_ + lane + 64] = e1 * inv;
}

// ---------------- context: block (b, l-chunk of 64), 128 threads, float4 ----------------
__global__ void k_context(const float* __restrict__ enc, const float* __restrict__ attn,
                          float* __restrict__ comb) {
    int b = blockIdx.x;
    int l0 = blockIdx.y << 6;
    int tid = threadIdx.x;               // 128 threads, h4 = tid*4
    __shared__ float a_s[64];
    if (tid < 64) a_s[tid] = attn[(l0 + tid) * B_ + b];
    __syncthreads();
    const float4* e = (const float4*)(enc + ((size_t)l0 * B_ + b) * H2_) + tid;
    float4 c = make_float4(0.f, 0.f, 0.f, 0.f);
    #pragma unroll 8
    for (int i = 0; i < 64; ++i) {
        float4 x = e[(size_t)i * (B_ * H2_ / 4)];
        float a = a_s[i];
        c.x += a * x.x; c.y += a * x.y; c.z += a * x.z; c.w += a * x.w;
    }
    float* dst = comb + b * (2 * H2_) + H2_ + tid * 4;
    atomicAdd(dst + 0, c.x); atomicAdd(dst + 1, c.y);
    atomicAdd(dst + 2, c.z); atomicAdd(dst + 3, c.w);
}

// ---------------- p_gen: one wave per b ----------------
__global__ void k_pgen(const float* __restrict__ comb,
                       const int* __restrict__ ids, const float* __restrict__ tab,
                       const float* __restrict__ W_ptr, const float* __restrict__ b_ptr,
                       float* __restrict__ pgen) {
    int b = blockIdx.x, lane = threadIdx.x;  // 64 threads
    float s = 0.f;
    for (int j = lane; j < 2 * H2_; j += 64) s += W_ptr[j] * comb[b * (2 * H2_) + j];
    const float* erow = tab + (size_t)ids[b] * E_;
    for (int j = lane; j < E_; j += 64) s += W_ptr[2 * H2_ + j] * erow[j];
    #pragma unroll
    for (int o = 32; o; o >>= 1) s += __shfl_xor(s, o);
    if (lane == 0) pgen[b] = fast_sigmoid(s + b_ptr[0]);
}

// ---------------- vocab MFMA GEMM: out = exp(hid@Wov^T + bov), rsum8 partials --------
__global__ void k_vocab(const float* __restrict__ hid, const float* __restrict__ Wov,
                        const float* __restrict__ bov, float* __restrict__ out,
                        float* __restrict__ rsum8) {
    __shared__ float sm[4][128];
    int L = threadIdx.x & 63, w = threadIdx.x >> 6;
    int lrow = L & 15, lk = L >> 4;
    int n0 = blockIdx.x * 128 + w * 32;

    bf16x8 bfr[2][4];
    #pragma unroll
    for (int nt = 0; nt < 2; ++nt) {
        int n = n0 + nt * 16 + lrow;
        #pragma unroll
        for (int kk = 0; kk < 4; ++kk) {
            bf16x8 f;
            if (n < V_) {
                const float* p = Wov + (size_t)n * 128 + kk * 32 + lk * 8;
                float4 x = *(const float4*)p, y = *(const float4*)(p + 4);
                f[0]=f2bf(x.x); f[1]=f2bf(x.y); f[2]=f2bf(x.z); f[3]=f2bf(x.w);
                f[4]=f2bf(y.x); f[5]=f2bf(y.y); f[6]=f2bf(y.z); f[7]=f2bf(y.w);
            } else {
                #pragma unroll
                for (int j = 0; j < 8; ++j) f[j] = 0;
            }
            bfr[nt][kk] = f;
        }
    }
    f32x4 acc[8][2] = {};
    #pragma unroll
    for (int mt = 0; mt < 8; ++mt) {
        bf16x8 afr[4];
        #pragma unroll
        for (int kk = 0; kk < 4; ++kk) {
            const float* p = hid + (size_t)(mt * 16 + lrow) * 128 + kk * 32 + lk * 8;
            float4 x = *(const float4*)p, y = *(const float4*)(p + 4);
            bf16x8 f;
            f[0]=f2bf(x.x); f[1]=f2bf(x.y); f[2]=f2bf(x.z); f[3]=f2bf(x.w);
            f[4]=f2bf(y.x); f[5]=f2bf(y.y); f[6]=f2bf(y.z); f[7]=f2bf(y.w);
            afr[kk] = f;
        }
        #pragma unroll
        for (int nt = 0; nt < 2; ++nt)
            #pragma unroll
            for (int kk = 0; kk < 4; ++kk)
                acc[mt][nt] = __builtin_amdgcn_mfma_f32_16x16x32_bf16(
                    afr[kk], bfr[nt][kk], acc[mt][nt], 0, 0, 0);
    }
    float bv[2];
    #pragma unroll
    for (int nt = 0; nt < 2; ++nt) {
        int n = n0 + nt * 16 + lrow;
        bv[nt] = (n < V_) ? bov[n] : 0.f;
    }
    float rs[8][4];
    #pragma unroll
    for (int mt = 0; mt < 8; ++mt) {
        #pragma unroll
        for (int r = 0; r < 4; ++r) rs[mt][r] = 0.f;
        #pragma unroll
        for (int nt = 0; nt < 2; ++nt) {
            int n = n0 + nt * 16 + lrow;
            if (n < V_) {
                #pragma unroll
                for (int r = 0; r < 4; ++r) {
                    int row = mt * 16 + lk * 4 + r;
                    float e = __expf(acc[mt][nt][r] + bv[nt]);
                    out[(size_t)row * VL_ + n] = e;
                    rs[mt][r] += e;
                }
            }
        }
    }
    #pragma unroll
    for (int o = 1; o < 16; o <<= 1)
        #pragma unroll
        for (int mt = 0; mt < 8; ++mt)
            #pragma unroll
            for (int r = 0; r < 4; ++r) rs[mt][r] += __shfl_xor(rs[mt][r], o);
    if (lrow == 0) {
        #pragma unroll
        for (int mt = 0; mt < 8; ++mt)
            #pragma unroll
            for (int r = 0; r < 4; ++r)
                sm[w][mt * 16 + lk * 4 + r] = rs[mt][r];
    }
    __syncthreads();
    if (threadIdx.x < 128) {
        float p = sm[0][threadIdx.x] + sm[1][threadIdx.x]
                + sm[2][threadIdx.x] + sm[3][threadIdx.x];
        atomicAdd(&rsum8[(blockIdx.x & 7) * 128 + threadIdx.x], p);
    }
}

// ---------------- finalize: scale row chunk by pgen/rsum ----------------
__global__ void k_final(float* __restrict__ out, const float* __restrict__ pgen,
                        const float* __restrict__ rsum8) {
    int b = blockIdx.y, chunk = blockIdx.x, tid = threadIdx.x;
    __shared__ float sc;
    if (tid == 0) {
        float s = 0.f;
        #pragma unroll
        for (int j = 0; j < 8; ++j) s += rsum8[j * 128 + b];
        sc = pgen[b] / s;
    }
    __syncthreads();
    int j = chunk * 256 + tid;
    if (j < V_ / 4) {
        float4* p = (float4*)(out + (size_t)b * VL_) + j;
        float4 x = *p;
        x.x *= sc; x.y *= sc; x.z *= sc; x.w *= sc;
        *p = x;
    }
}

// ---------------- scatter copy distribution ----------------
__global__ void k_scatter(float* __restrict__ out, const int* __restrict__ full_input,
                          const float* __restrict__ attn, const float* __restrict__ pgen) {
    int idx = blockIdx.x * blockDim.x + threadIdx.x;  // L*B = 65536
    int b = idx & 127;
    int tok = full_input[idx];
    atomicAdd(&out[(size_t)b * VL_ + tok], (1.f - pgen[b]) * attn[idx]);
}

extern "C" void kernel_launch(void* const* d_in, const int* in_sizes, int n_in,
                              void* d_out, int out_size, void* d_ws, size_t ws_size,
                              hipStream_t stream) {
    const int*   input_ids = (const int*)d_in[0];
    const float* hidden    = (const float*)d_in[1];
    const float* enc       = (const float*)d_in[2];
    const int*   full_in   = (const int*)d_in[3];
    const float* emb_tab   = (const float*)d_in[4];
    const float* W_ih      = (const float*)d_in[5];
    const float* W_hh      = (const float*)d_in[6];
    const float* b_ih      = (const float*)d_in[7];
    const float* b_hh      = (const float*)d_in[8];
    const float* W_ds      = (const float*)d_in[9];
    const float* b_ds      = (const float*)d_in[10];
    const float* w_h       = (const float*)d_in[11];
    const float* att_v     = (const float*)d_in[12];
    const float* W_oh      = (const float*)d_in[13];
    const float* b_oh      = (const float*)d_in[14];
    const float* W_ov      = (const float*)d_in[15];
    const float* b_ov      = (const float*)d_in[16];
    const float* W_ptr     = (const float*)d_in[17];
    const float* b_ptr     = (const float*)d_in[18];

    float* out = (float*)d_out;
    float* p_final = out;                                  // [B, VL]
    float* h_out   = out + (size_t)B_ * VL_;               // [B, H2]
    float* attn    = out + (size_t)B_ * VL_ + B_ * H2_;    // [L, B]

    float* ws = (float*)d_ws;
    float* gx     = ws;            // 196608
    float* gh     = gx + 196608;   // 196608
    float* comb   = gh + 196608;   // 131072  [B, 2*H2]: h_new | context
    float* dsl    = comb + 131072; // 65536
    float* scores = dsl + 65536;   // 65536
    float* hid    = scores + 65536;// 16384
    float* pgen   = hid + 16384;   // 128
    float* rsum8  = pgen + 128;    // 1024

    // 0. init bias targets / zero pad & rsum8
    k_init<<<dim3(2116), dim3(256), 0, stream>>>(gx, gh, dsl, hid, out, rsum8,
                                                 b_ih, b_hh, b_ds, b_oh);
    // 1. gx & gh GEMMs (split-K, atomic)
    k_gates<<<dim3(4,48,6), dim3(256), 0, stream>>>(input_ids, emb_tab, hidden,
                                                    W_ih, W_hh, gx, gh);
    // 2. GRU -> h_new (+ zero ctx region)
    k_gru<<<dim3(256), dim3(256), 0, stream>>>(gx, gh, hidden, comb, h_out);
    // 3. dsl = h_new @ W_ds^T + b_ds (split-K 4)
    gemm_t<32,32,32,2,2,4><<<dim3(4,16,4), dim3(256), 0, stream>>>(
        comb, 2*H2_, W_ds, H2_, dsl, H2_, H2_, H2_);
    // 4. attention scores (8 l's per wave)
    k_scores<<<dim3(2048), dim3(256), 0, stream>>>(enc, dsl, w_h, att_v, scores);
    // 5. softmax over batch axis
    k_softmax<<<dim3(L_), dim3(64), 0, stream>>>(scores, attn);
    // 6. context (64-l chunks, as in R6)
    k_context<<<dim3(B_, 8), dim3(128), 0, stream>>>(enc, attn, comb);
    // 7. p_gen
    k_pgen<<<dim3(B_), dim3(64), 0, stream>>>(comb, input_ids, emb_tab, W_ptr, b_ptr, pgen);
    // 8. hid = comb @ W_oh^T + b_oh (split-K 8)
    gemm_t<32,32,32,2,2,8><<<dim3(4,4,8), dim3(256), 0, stream>>>(
        comb, 2*H2_, W_oh, 2*H2_, hid, E_, E_, 2*H2_);
    // 9. vocab MFMA: out = exp(logits) f32, rsum8 partials
    k_vocab<<<dim3(391), dim3(256), 0, stream>>>(hid, W_ov, b_ov, p_final, rsum8);
    // 10. scale by pgen/rsum (in place, L3-resident)
    k_final<<<dim3(49, 128), dim3(256), 0, stream>>>(p_final, pgen, rsum8);
    // 11. scatter
    k_scatter<<<dim3(L_*B_/256), dim3(256), 0, stream>>>(p_final, full_in, attn, pgen);
}

// Round 9
// 140.359 us; speedup vs baseline: 1.1063x; 1.0422x over previous
//
#include <hip/hip_runtime.h>
#include <math.h>

#define B_  128
#define E_  128
#define H2_ 512
#define H3_ 1536
#define L_  512
#define V_  50000
#define VL_ 50512   // V + L

typedef short bf16x8 __attribute__((ext_vector_type(8)));
typedef float f32x4 __attribute__((ext_vector_type(4)));

__device__ __forceinline__ float fast_tanh(float x) {
    float e = __expf(2.f * x);
    return 1.f - 2.f / (e + 1.f);
}
__device__ __forceinline__ float fast_sigmoid(float x) {
    return 1.f / (1.f + __expf(-x));
}
__device__ __forceinline__ short f2bf(float f) {
    unsigned u = __float_as_uint(f);
    u += 0x7fff + ((u >> 16) & 1);        // RNE
    return (short)(u >> 16);
}

// ---------------- gx & gh GEMMs, split-K -> PARTIAL buffers (no atomics) -------------
// z: 0-1 -> gxp[z] (K=128 halves), 2-5 -> ghp[z-2] (K=512 quarters)
__global__ void k_gates(const int* __restrict__ ids, const float* __restrict__ tab,
                        const float* __restrict__ hidden,
                        const float* __restrict__ W_ih, const float* __restrict__ W_hh,
                        float* __restrict__ gxp, float* __restrict__ ghp) {
    __shared__ float As[32][36];
    __shared__ float Ws[32][36];
    int z = blockIdx.z;
    int which = (z < 2) ? 0 : 1;
    int kbeg  = which ? (z - 2) * 128 : z * 64;
    int kiter = which ? 4 : 2;
    const float* W = which ? W_hh : W_ih;
    int ldw = which ? H2_ : E_;
    float* C = which ? (ghp + (size_t)(z - 2) * B_ * H3_) : (gxp + (size_t)z * B_ * H3_);
    int bm = blockIdx.x * 32, bn = blockIdx.y * 32;
    int tid = threadIdx.x;
    int tm0 = (tid / 16) * 2, tn0 = (tid % 16) * 2;
    float acc[2][2] = {};
    for (int it = 0; it < kiter; ++it) {
        int k0 = kbeg + it * 32;
        for (int v = tid; v < 256; v += 256) {
            int m = v >> 3, q = (v & 7) << 2;
            int gm = bm + m;
            const float* arow = which ? (hidden + (size_t)gm * H2_)
                                      : (tab + (size_t)ids[gm] * E_);
            float4 x = *(const float4*)(arow + k0 + q);
            As[q+0][m] = x.x; As[q+1][m] = x.y; As[q+2][m] = x.z; As[q+3][m] = x.w;
        }
        for (int v = tid; v < 256; v += 256) {
            int n = v >> 3, q = (v & 7) << 2;
            float4 x = *(const float4*)(W + (size_t)(bn + n) * ldw + k0 + q);
            Ws[q+0][n] = x.x; Ws[q+1][n] = x.y; Ws[q+2][n] = x.z; Ws[q+3][n] = x.w;
        }
        __syncthreads();
        #pragma unroll
        for (int kk = 0; kk < 32; ++kk) {
            float a0 = As[kk][tm0], a1 = As[kk][tm0+1];
            float w0 = Ws[kk][tn0], w1 = Ws[kk][tn0+1];
            acc[0][0] += a0*w0; acc[0][1] += a0*w1;
            acc[1][0] += a1*w0; acc[1][1] += a1*w1;
        }
        __syncthreads();
    }
    #pragma unroll
    for (int i = 0; i < 2; ++i)
        #pragma unroll
        for (int j = 0; j < 2; ++j)
            C[(size_t)(bm+tm0+i) * H3_ + bn+tn0+j] = acc[i][j];
}

// ---------------- generic tiled GEMM, split-K: partial-store or atomic ----------------
template<int BM, int BN, int BK, int TM, int TN, int SPLITK, bool ATOMIC>
__global__ void gemm_t(const float* __restrict__ A, int lda,
                       const float* __restrict__ W, int ldw,
                       float* __restrict__ C, int ldc,
                       int N, int K, int partElems) {
    __shared__ float As[BK][BM + 4];
    __shared__ float Ws[BK][BN + 4];
    int bm = blockIdx.x * BM, bn = blockIdx.y * BN;
    int tid = threadIdx.x;
    constexpr int NT = BN / TN;
    int tm0 = (tid / NT) * TM;
    int tn0 = (tid % NT) * TN;
    int kchunk = K / SPLITK;
    int kbeg = blockIdx.z * kchunk;
    float acc[TM][TN] = {};
    for (int k0 = kbeg; k0 < kbeg + kchunk; k0 += BK) {
        #pragma unroll
        for (int v = tid; v < BM * BK / 4; v += 256) {
            int m = v / (BK / 4), q = (v % (BK / 4)) * 4;
            float4 x = *(const float4*)(A + (size_t)(bm + m) * lda + k0 + q);
            As[q+0][m] = x.x; As[q+1][m] = x.y; As[q+2][m] = x.z; As[q+3][m] = x.w;
        }
        #pragma unroll
        for (int v = tid; v < BN * BK / 4; v += 256) {
            int n = v / (BK / 4), q = (v % (BK / 4)) * 4;
            float4 x = *(const float4*)(W + (size_t)(bn + n) * ldw + k0 + q);
            Ws[q+0][n] = x.x; Ws[q+1][n] = x.y; Ws[q+2][n] = x.z; Ws[q+3][n] = x.w;
        }
        __syncthreads();
        #pragma unroll
        for (int kk = 0; kk < BK; ++kk) {
            float a[TM], w[TN];
            #pragma unroll
            for (int i = 0; i < TM; ++i) a[i] = As[kk][tm0 + i];
            #pragma unroll
            for (int j = 0; j < TN; ++j) w[j] = Ws[kk][tn0 + j];
            #pragma unroll
            for (int i = 0; i < TM; ++i)
                #pragma unroll
                for (int j = 0; j < TN; ++j) acc[i][j] += a[i] * w[j];
        }
        __syncthreads();
    }
    float* Cz = ATOMIC ? C : (C + (size_t)blockIdx.z * partElems);
    #pragma unroll
    for (int i = 0; i < TM; ++i)
        #pragma unroll
        for (int j = 0; j < TN; ++j) {
            if (ATOMIC) atomicAdd(&Cz[(size_t)(bm+tm0+i) * ldc + bn+tn0+j], acc[i][j]);
            else        Cz[(size_t)(bm+tm0+i) * ldc + bn+tn0+j] = acc[i][j];
        }
}

// ---------------- GRU gates: reduce gate partials + biases; init hid/rsum8 -----------
__global__ void k_gru(const float* __restrict__ gxp, const float* __restrict__ ghp,
                      const float* __restrict__ b_ih, const float* __restrict__ b_hh,
                      const float* __restrict__ h0, const float* __restrict__ b_oh,
                      float* __restrict__ comb, float* __restrict__ hout,
                      float* __restrict__ hid, float* __restrict__ rsum8) {
    int idx = blockIdx.x * blockDim.x + threadIdx.x;  // B*H2 = 65536
    int b = idx >> 9, h = idx & 511;
    const float* gx0 = gxp + (size_t)b * H3_;
    const float* gx1 = gx0 + (size_t)B_ * H3_;
    float xr = gx0[h]         + gx1[h]         + b_ih[h];
    float xz = gx0[H2_+h]     + gx1[H2_+h]     + b_ih[H2_+h];
    float xn = gx0[2*H2_+h]   + gx1[2*H2_+h]   + b_ih[2*H2_+h];
    float hr = b_hh[h], hz = b_hh[H2_+h], hn = b_hh[2*H2_+h];
    #pragma unroll
    for (int z = 0; z < 4; ++z) {
        const float* g = ghp + ((size_t)z * B_ + b) * H3_;
        hr += g[h]; hz += g[H2_+h]; hn += g[2*H2_+h];
    }
    float r = fast_sigmoid(xr + hr);
    float zz = fast_sigmoid(xz + hz);
    float n = fast_tanh(xn + r * hn);
    float hv = (1.f - zz) * n + zz * h0[idx];
    comb[b * (2 * H2_) + h] = hv;
    hout[idx] = hv;
    if (idx < B_ * E_) hid[idx] = b_oh[idx & 127];   // split-K atomic target init
    if (idx < 1024)    rsum8[idx] = 0.f;
}

// ---------------- attention scores: one wave = 8 l's x same b; dsl from partials -----
__global__ void k_scores(const float* __restrict__ enc, const float* __restrict__ dslp,
                         const float* __restrict__ b_ds,
                         const float* __restrict__ w_h, const float* __restrict__ att_v,
                         float* __restrict__ scores) {
    int wid = (blockIdx.x << 2) + (threadIdx.x >> 6);  // 8192 waves
    int lane = threadIdx.x & 63;
    int b = wid & 127, lg = wid >> 7;                  // 64 l-groups of 8
    int l0 = lg << 3;
    const float4* w4 = (const float4*)w_h;
    const float4* v4 = (const float4*)att_v;
    const float4* bd4 = (const float4*)b_ds;
    float4 d0 = bd4[lane], d1 = bd4[lane + 64];
    #pragma unroll
    for (int z = 0; z < 4; ++z) {
        const float4* dp = (const float4*)(dslp + (size_t)z * B_ * H2_ + b * H2_);
        float4 p0 = dp[lane], p1 = dp[lane + 64];
        d0.x += p0.x; d0.y += p0.y; d0.z += p0.z; d0.w += p0.w;
        d1.x += p1.x; d1.y += p1.y; d1.z += p1.z; d1.w += p1.w;
    }
    float4 w0 = w4[lane], w1 = w4[lane + 64];
    float4 v0 = v4[lane], v1 = v4[lane + 64];
    float4 e0[8], e1[8];
    #pragma unroll
    for (int q = 0; q < 8; ++q) {
        const float4* e4 = (const float4*)(enc + ((size_t)((l0 + q) * B_ + b)) * H2_);
        e0[q] = e4[lane];
        e1[q] = e4[lane + 64];
    }
    float s[8];
    #pragma unroll
    for (int q = 0; q < 8; ++q) {
        float t;
        t  = v0.x * fast_tanh(w0.x * e0[q].x + d0.x);
        t += v0.y * fast_tanh(w0.y * e0[q].y + d0.y);
        t += v0.z * fast_tanh(w0.z * e0[q].z + d0.z);
        t += v0.w * fast_tanh(w0.w * e0[q].w + d0.w);
        t += v1.x * fast_tanh(w1.x * e1[q].x + d1.x);
        t += v1.y * fast_tanh(w1.y * e1[q].y + d1.y);
        t += v1.z * fast_tanh(w1.z * e1[q].z + d1.z);
        t += v1.w * fast_tanh(w1.w * e1[q].w + d1.w);
        s[q] = t;
    }
    #pragma unroll
    for (int q = 0; q < 8; ++q) {
        float t = s[q];
        #pragma unroll
        for (int o = 32; o; o >>= 1) t += __shfl_xor(t, o);
        if (lane == 0) scores[(l0 + q) * B_ + b] = t;
    }
}

// ---------------- softmax over batch axis (per l) ----------------
__global__ void k_softmax(const float* __restrict__ scores, float* __restrict__ attn) {
    int l = blockIdx.x, lane = threadIdx.x;   // 64 threads
    float s0 = scores[l * B_ + lane], s1 = scores[l * B_ + lane + 64];
    float m = fmaxf(s0, s1);
    #pragma unroll
    for (int o = 32; o; o >>= 1) m = fmaxf(m, __shfl_xor(m, o));
    float e0 = __expf(s0 - m), e1 = __expf(s1 - m);
    float t = e0 + e1;
    #pragma unroll
    for (int o = 32; o; o >>= 1) t += __shfl_xor(t, o);
    float inv = 1.f / t;
    attn[l * B_ + lane] = e0 * inv;
    attn[l * B_ + lane + 64] = e1 * inv;
}

// ---------------- context partials: block (b, l-chunk of 64), plain stores -----------
__global__ void k_context(const float* __restrict__ enc, const float* __restrict__ attn,
                          float* __restrict__ ctxp) {
    int b = blockIdx.x;
    int l0 = blockIdx.y << 6;
    int tid = threadIdx.x;               // 128 threads, float4 over h
    __shared__ float a_s[64];
    if (tid < 64) a_s[tid] = attn[(l0 + tid) * B_ + b];
    __syncthreads();
    const float4* e = (const float4*)(enc + ((size_t)l0 * B_ + b) * H2_) + tid;
    float4 c = make_float4(0.f, 0.f, 0.f, 0.f);
    #pragma unroll 8
    for (int i = 0; i < 64; ++i) {
        float4 x = e[(size_t)i * (B_ * H2_ / 4)];
        float a = a_s[i];
        c.x += a * x.x; c.y += a * x.y; c.z += a * x.z; c.w += a * x.w;
    }
    ((float4*)(ctxp + ((size_t)blockIdx.y * B_ + b) * H2_))[tid] = c;
}

// ---------------- ctx reduce + p_gen: 128 blocks x 128 thr ----------------
__global__ void k_ctxpgen(const float* __restrict__ ctxp, const int* __restrict__ ids,
                          const float* __restrict__ tab, const float* __restrict__ W_ptr,
                          const float* __restrict__ b_ptr,
                          float* __restrict__ comb, float* __restrict__ pgen) {
    __shared__ float red[128];
    int b = blockIdx.x, tid = threadIdx.x;   // h4 = tid
    float4 c = make_float4(0.f, 0.f, 0.f, 0.f);
    #pragma unroll
    for (int z = 0; z < 8; ++z) {
        float4 x = ((const float4*)(ctxp + ((size_t)z * B_ + b) * H2_))[tid];
        c.x += x.x; c.y += x.y; c.z += x.z; c.w += x.w;
    }
    ((float4*)(comb + b * (2 * H2_) + H2_))[tid] = c;
    const float4* wp = (const float4*)W_ptr;
    float4 wc = wp[128 + tid];                       // ctx part of W_ptr
    float s = c.x * wc.x + c.y * wc.y + c.z * wc.z + c.w * wc.w;
    float4 hv = ((const float4*)(comb + b * (2 * H2_)))[tid];
    float4 wh = wp[tid];                             // h_new part
    s += hv.x * wh.x + hv.y * wh.y + hv.z * wh.z + hv.w * wh.w;
    if (tid < 32) {                                  // emb part (128 floats)
        float4 ev = ((const float4*)(tab + (size_t)ids[b] * E_))[tid];
        float4 we = wp[256 + tid];
        s += ev.x * we.x + ev.y * we.y + ev.z * we.z + ev.w * we.w;
    }
    red[tid] = s;
    __syncthreads();
    if (tid < 64) {
        float t = red[tid] + red[tid + 64];
        #pragma unroll
        for (int o = 32; o; o >>= 1) t += __shfl_xor(t, o);
        if (tid == 0) pgen[b] = fast_sigmoid(t + b_ptr[0]);
    }
}

// ---------------- vocab MFMA pass 1: rsum8 only (no stores of exp) ----------------
__global__ void k_vsum(const float* __restrict__ hid, const float* __restrict__ Wov,
                       const float* __restrict__ bov, float* __restrict__ rsum8) {
    __shared__ float sm[4][128];
    int L = threadIdx.x & 63, w = threadIdx.x >> 6;
    int lrow = L & 15, lk = L >> 4;
    int n0 = blockIdx.x * 128 + w * 32;

    bf16x8 bfr[2][4];
    #pragma unroll
    for (int nt = 0; nt < 2; ++nt) {
        int n = n0 + nt * 16 + lrow;
        #pragma unroll
        for (int kk = 0; kk < 4; ++kk) {
            bf16x8 f;
            if (n < V_) {
                const float* p = Wov + (size_t)n * 128 + kk * 32 + lk * 8;
                float4 x = *(const float4*)p, y = *(const float4*)(p + 4);
                f[0]=f2bf(x.x); f[1]=f2bf(x.y); f[2]=f2bf(x.z); f[3]=f2bf(x.w);
                f[4]=f2bf(y.x); f[5]=f2bf(y.y); f[6]=f2bf(y.z); f[7]=f2bf(y.w);
            } else {
                #pragma unroll
                for (int j = 0; j < 8; ++j) f[j] = 0;
            }
            bfr[nt][kk] = f;
        }
    }
    f32x4 acc[8][2] = {};
    #pragma unroll
    for (int mt = 0; mt < 8; ++mt) {
        bf16x8 afr[4];
        #pragma unroll
        for (int kk = 0; kk < 4; ++kk) {
            const float* p = hid + (size_t)(mt * 16 + lrow) * 128 + kk * 32 + lk * 8;
            float4 x = *(const float4*)p, y = *(const float4*)(p + 4);
            bf16x8 f;
            f[0]=f2bf(x.x); f[1]=f2bf(x.y); f[2]=f2bf(x.z); f[3]=f2bf(x.w);
            f[4]=f2bf(y.x); f[5]=f2bf(y.y); f[6]=f2bf(y.z); f[7]=f2bf(y.w);
            afr[kk] = f;
        }
        #pragma unroll
        for (int nt = 0; nt < 2; ++nt)
            #pragma unroll
            for (int kk = 0; kk < 4; ++kk)
                acc[mt][nt] = __builtin_amdgcn_mfma_f32_16x16x32_bf16(
                    afr[kk], bfr[nt][kk], acc[mt][nt], 0, 0, 0);
    }
    float bv[2];
    #pragma unroll
    for (int nt = 0; nt < 2; ++nt) {
        int n = n0 + nt * 16 + lrow;
        bv[nt] = (n < V_) ? bov[n] : 0.f;
    }
    float rs[8][4];
    #pragma unroll
    for (int mt = 0; mt < 8; ++mt) {
        #pragma unroll
        for (int r = 0; r < 4; ++r) rs[mt][r] = 0.f;
        #pragma unroll
        for (int nt = 0; nt < 2; ++nt) {
            int n = n0 + nt * 16 + lrow;
            if (n < V_) {
                #pragma unroll
                for (int r = 0; r < 4; ++r)
                    rs[mt][r] += __expf(acc[mt][nt][r] + bv[nt]);
            }
        }
    }
    #pragma unroll
    for (int o = 1; o < 16; o <<= 1)
        #pragma unroll
        for (int mt = 0; mt < 8; ++mt)
            #pragma unroll
            for (int r = 0; r < 4; ++r) rs[mt][r] += __shfl_xor(rs[mt][r], o);
    if (lrow == 0) {
        #pragma unroll
        for (int mt = 0; mt < 8; ++mt)
            #pragma unroll
            for (int r = 0; r < 4; ++r)
                sm[w][mt * 16 + lk * 4 + r] = rs[mt][r];
    }
    __syncthreads();
    if (threadIdx.x < 128) {
        float p = sm[0][threadIdx.x] + sm[1][threadIdx.x]
                + sm[2][threadIdx.x] + sm[3][threadIdx.x];
        atomicAdd(&rsum8[(blockIdx.x & 7) * 128 + threadIdx.x], p);
    }
}

// ---------------- vocab MFMA pass 2: recompute logits, scale, write (+pad) -----------
__global__ void k_vwrite(const float* __restrict__ hid, const float* __restrict__ Wov,
                         const float* __restrict__ bov, const float* __restrict__ pgen,
                         const float* __restrict__ rsum8, float* __restrict__ out) {
    __shared__ float scs[128];
    if (blockIdx.x == 391) {     // pad-zero block group: zero out[:, V:V+L)
        for (int i = threadIdx.x; i < B_ * (L_ / 4); i += 256) {
            int b = i >> 7, k = i & 127;
            ((float4*)(out + (size_t)b * VL_ + V_))[k] = make_float4(0.f,0.f,0.f,0.f);
        }
        return;
    }
    if (threadIdx.x < 128) {
        float s = 0.f;
        #pragma unroll
        for (int j = 0; j < 8; ++j) s += rsum8[j * 128 + threadIdx.x];
        scs[threadIdx.x] = pgen[threadIdx.x] / s;
    }
    __syncthreads();
    int L = threadIdx.x & 63, w = threadIdx.x >> 6;
    int lrow = L & 15, lk = L >> 4;
    int n0 = blockIdx.x * 128 + w * 32;

    bf16x8 bfr[2][4];
    #pragma unroll
    for (int nt = 0; nt < 2; ++nt) {
        int n = n0 + nt * 16 + lrow;
        #pragma unroll
        for (int kk = 0; kk < 4; ++kk) {
            bf16x8 f;
            if (n < V_) {
                const float* p = Wov + (size_t)n * 128 + kk * 32 + lk * 8;
                float4 x = *(const float4*)p, y = *(const float4*)(p + 4);
                f[0]=f2bf(x.x); f[1]=f2bf(x.y); f[2]=f2bf(x.z); f[3]=f2bf(x.w);
                f[4]=f2bf(y.x); f[5]=f2bf(y.y); f[6]=f2bf(y.z); f[7]=f2bf(y.w);
            } else {
                #pragma unroll
                for (int j = 0; j < 8; ++j) f[j] = 0;
            }
            bfr[nt][kk] = f;
        }
    }
    f32x4 acc[8][2] = {};
    #pragma unroll
    for (int mt = 0; mt < 8; ++mt) {
        bf16x8 afr[4];
        #pragma unroll
        for (int kk = 0; kk < 4; ++kk) {
            const float* p = hid + (size_t)(mt * 16 + lrow) * 128 + kk * 32 + lk * 8;
            float4 x = *(const float4*)p, y = *(const float4*)(p + 4);
            bf16x8 f;
            f[0]=f2bf(x.x); f[1]=f2bf(x.y); f[2]=f2bf(x.z); f[3]=f2bf(x.w);
            f[4]=f2bf(y.x); f[5]=f2bf(y.y); f[6]=f2bf(y.z); f[7]=f2bf(y.w);
            afr[kk] = f;
        }
        #pragma unroll
        for (int nt = 0; nt < 2; ++nt)
            #pragma unroll
            for (int kk = 0; kk < 4; ++kk)
                acc[mt][nt] = __builtin_amdgcn_mfma_f32_16x16x32_bf16(
                    afr[kk], bfr[nt][kk], acc[mt][nt], 0, 0, 0);
    }
    float bv[2];
    #pragma unroll
    for (int nt = 0; nt < 2; ++nt) {
        int n = n0 + nt * 16 + lrow;
        bv[nt] = (n < V_) ? bov[n] : 0.f;
    }
    #pragma unroll
    for (int mt = 0; mt < 8; ++mt) {
        #pragma unroll
        for (int nt = 0; nt < 2; ++nt) {
            int n = n0 + nt * 16 + lrow;
            if (n < V_) {
                #pragma unroll
                for (int r = 0; r < 4; ++r) {
                    int row = mt * 16 + lk * 4 + r;
                    out[(size_t)row * VL_ + n] =
                        __expf(acc[mt][nt][r] + bv[nt]) * scs[row];
                }
            }
        }
    }
}

// ---------------- scatter copy distribution ----------------
__global__ void k_scatter(float* __restrict__ out, const int* __restrict__ full_input,
                          const float* __restrict__ attn, const float* __restrict__ pgen) {
    int idx = blockIdx.x * blockDim.x + threadIdx.x;  // L*B = 65536
    int b = idx & 127;
    int tok = full_input[idx];
    atomicAdd(&out[(size_t)b * VL_ + tok], (1.f - pgen[b]) * attn[idx]);
}

extern "C" void kernel_launch(void* const* d_in, const int* in_sizes, int n_in,
                              void* d_out, int out_size, void* d_ws, size_t ws_size,
                              hipStream_t stream) {
    const int*   input_ids = (const int*)d_in[0];
    const float* hidden    = (const float*)d_in[1];
    const float* enc       = (const float*)d_in[2];
    const int*   full_in   = (const int*)d_in[3];
    const float* emb_tab   = (const float*)d_in[4];
    const float* W_ih      = (const float*)d_in[5];
    const float* W_hh      = (const float*)d_in[6];
    const float* b_ih      = (const float*)d_in[7];
    const float* b_hh      = (const float*)d_in[8];
    const float* W_ds      = (const float*)d_in[9];
    const float* b_ds      = (const float*)d_in[10];
    const float* w_h       = (const float*)d_in[11];
    const float* att_v     = (const float*)d_in[12];
    const float* W_oh      = (const float*)d_in[13];
    const float* b_oh      = (const float*)d_in[14];
    const float* W_ov      = (const float*)d_in[15];
    const float* b_ov      = (const float*)d_in[16];
    const float* W_ptr     = (const float*)d_in[17];
    const float* b_ptr     = (const float*)d_in[18];

    float* out = (float*)d_out;
    float* p_final = out;                                  // [B, VL]
    float* h_out   = out + (size_t)B_ * VL_;               // [B, H2]
    float* attn    = out + (size_t)B_ * VL_ + B_ * H2_;    // [L, B]

    float* ws = (float*)d_ws;
    float* gxp    = ws;             // 2 * 196608 = 393216
    float* ghp    = gxp + 393216;   // 4 * 196608 = 786432
    float* comb   = ghp + 786432;   // 131072  [B, 2*H2]: h_new | context
    float* dslp   = comb + 131072;  // 4 * 65536 = 262144
    float* scores = dslp + 262144;  // 65536
    float* ctxp   = scores + 65536; // 8 * 65536 = 524288
    float* hid    = ctxp + 524288;  // 16384
    float* pgen   = hid + 16384;    // 128
    float* rsum8  = pgen + 128;     // 1024

    // 1. gx & gh gate GEMMs -> partial buffers (no atomics)
    k_gates<<<dim3(4,48,6), dim3(256), 0, stream>>>(input_ids, emb_tab, hidden,
                                                    W_ih, W_hh, gxp, ghp);
    // 2. GRU: reduce partials + biases -> h_new; init hid=b_oh, rsum8=0
    k_gru<<<dim3(256), dim3(256), 0, stream>>>(gxp, ghp, b_ih, b_hh, hidden, b_oh,
                                               comb, h_out, hid, rsum8);
    // 3. dsl partials (split-K 4, plain stores)
    gemm_t<32,32,32,2,2,4,false><<<dim3(4,16,4), dim3(256), 0, stream>>>(
        comb, 2*H2_, W_ds, H2_, dslp, H2_, H2_, H2_, B_*H2_);
    // 4. attention scores (8 l's per wave; dsl summed from partials + b_ds)
    k_scores<<<dim3(2048), dim3(256), 0, stream>>>(enc, dslp, b_ds, w_h, att_v, scores);
    // 5. softmax over batch axis
    k_softmax<<<dim3(L_), dim3(64), 0, stream>>>(scores, attn);
    // 6. context partials (plain stores)
    k_context<<<dim3(B_, 8), dim3(128), 0, stream>>>(enc, attn, ctxp);
    // 7. ctx reduce + p_gen
    k_ctxpgen<<<dim3(B_), dim3(128), 0, stream>>>(ctxp, input_ids, emb_tab,
                                                  W_ptr, b_ptr, comb, pgen);
    // 8. hid = comb @ W_oh^T + b_oh (split-K 8, atomic onto bias init)
    gemm_t<32,32,32,2,2,8,true><<<dim3(4,4,8), dim3(256), 0, stream>>>(
        comb, 2*H2_, W_oh, 2*H2_, hid, E_, E_, 2*H2_, 0);
    // 9. vocab pass 1: rsum8 partials only
    k_vsum<<<dim3(391), dim3(256), 0, stream>>>(hid, W_ov, b_ov, rsum8);
    // 10. vocab pass 2: recompute, scale, write p_final (+ zero pad)
    k_vwrite<<<dim3(392), dim3(256), 0, stream>>>(hid, W_ov, b_ov, pgen, rsum8, p_final);
    // 11. scatter
    k_scatter<<<dim3(L_*B_/256), dim3(256), 0, stream>>>(p_final, full_in, attn, pgen);
}